// Round 10
// baseline (3512.536 us; speedup 1.0000x reference)
//
#include <hip/hip_runtime.h>
#include <stdint.h>

typedef _Float16 half8 __attribute__((ext_vector_type(8)));  // 8 fp16 (4 VGPR) MFMA frag
typedef __attribute__((ext_vector_type(4))) float f4;        // fp32x4 accum
typedef __attribute__((ext_vector_type(4))) unsigned int u32x4;
typedef __attribute__((ext_vector_type(2))) unsigned int u32x2;

#define LDAH 200   // halves per LDS A row (192 data + 8 pad)
#define EXS  36    // exchange stride (floats); 144B row, 16B-aligned
#define HSTR 40    // sH stride (halves), 80B: 16B-aligned
#define SBS  584   // sB stride (halves): 576 data + 8 pad

__device__ __forceinline__ float sigm(float x) { return 1.0f / (1.0f + __expf(-x)); }
__device__ __forceinline__ float tanh_(float x) { return 1.0f - 2.0f / (__expf(2.0f * x) + 1.0f); } // overflow-safe

// ---- coherent accessors: volatile vector ops lower to single global_load/store_dwordx4
// with sc0 sc1 on gfx950 (cache-bypass to the coherence point) — same semantics as the
// R6 atomic-pair version (which PASSED), but 1 instruction per 16B and full wave
// coalescing instead of 2x8B atomics (R6's 431 MB / 660 GB/s killer).
__device__ __forceinline__ u32x4 cld128(const void* p) {
    return *(const volatile u32x4*)p;
}
__device__ __forceinline__ void cst128(void* p, u32x4 v) {
    *(volatile u32x4*)p = v;
}
__device__ __forceinline__ f4 cldf4(const void* p) {
    return *(const volatile f4*)p;
}
__device__ __forceinline__ void cst64v(void* p, u32x2 v) {
    *(volatile u32x2*)p = v;
}
__device__ __forceinline__ void cst32f(void* p, float v) {
    *(volatile float*)p = v;
}

// ---------------- prologue kernels ----------------

// W_catA[2048][576] = [W_ih | W_hh] fp16 ; also W_ih part of W_catB
extern "C" __global__ void __launch_bounds__(256) k_wcat(
    const float* __restrict__ Wih, const float* __restrict__ Whh,
    _Float16* __restrict__ WA, _Float16* __restrict__ WB)
{
    int idx = blockIdx.x * 256 + threadIdx.x;        // grid 4608 -> exactly 2048*576
    int n = idx / 576, k = idx % 576;
    float v = (k < 64) ? Wih[n * 64 + k] : Whh[n * 512 + (k - 64)];
    _Float16 b = (_Float16)v;
    WA[idx] = b;
    if (k < 64) WB[idx] = b;
}

// W_catB[n][64+k] = W_hh[n][k] + sum_p W_ih[n][p] * W_out[p][k]   (fp32 accum, fp16 store)
extern "C" __global__ void __launch_bounds__(256) k_comb(
    const float* __restrict__ Wih, const float* __restrict__ Whh,
    const float* __restrict__ Wo, _Float16* __restrict__ WB)
{
    int bx = blockIdx.x;                             // grid 4096
    int n = bx >> 1;
    int kh = ((bx & 1) << 8) + threadIdx.x;          // 0..511
    float acc = Whh[n * 512 + kh];
    #pragma unroll 16
    for (int p = 0; p < 64; ++p)
        acc += Wih[n * 64 + p] * Wo[p * 512 + kh];
    WB[n * 576 + 64 + kh] = (_Float16)acc;
}

// Wout fp16, bias0 = b_ih+b_hh, bias1 = bias0 + W_ih@b_out, y_{-1} init, group-barrier init
extern "C" __global__ void __launch_bounds__(256) k_misc(
    const float* __restrict__ Wo, const float* __restrict__ bih, const float* __restrict__ bhh,
    const float* __restrict__ Wih, const float* __restrict__ bo, const float* __restrict__ x,
    _Float16* __restrict__ WoB, float* __restrict__ b0v, float* __restrict__ b1v,
    float* __restrict__ yf0, float* __restrict__ yf1,
    _Float16* __restrict__ yh0, _Float16* __restrict__ yh1,
    _Float16* __restrict__ yl0, _Float16* __restrict__ yl1,
    unsigned* __restrict__ bar)
{
    int idx = blockIdx.x * 256 + threadIdx.x;        // grid 396
    if (idx < 32768) { WoB[idx] = (_Float16)Wo[idx]; return; }
    if (idx < 34816) {
        int n = idx - 32768;
        float b = bih[n] + bhh[n];
        b0v[n] = b;
        float a = b;
        #pragma unroll 16
        for (int p = 0; p < 64; ++p) a += Wih[n * 64 + p] * bo[p];
        b1v[n] = a;
        return;
    }
    if (idx < 100352) {
        int e = idx - 34816;
        int m = e >> 6, nn = e & 63;
        float v = x[m * 2048 + 31 * 64 + nn];        // x[:, -1, :]
        yf0[e] = v; yf1[e] = v;
        _Float16 hi = (_Float16)v;
        _Float16 lo = (_Float16)(v - (float)hi);
        yh0[e] = hi; yh1[e] = hi;
        yl0[e] = lo; yl1[e] = lo;
        return;
    }
    if (idx < 101376) bar[idx - 100352] = 0u;        // 16 groups x 64 words (256B spacing)
}

// h0 = z @ Wproj^T + b_proj ; c0 = h0 ; h stored fp16 hi/lo
extern "C" __global__ void __launch_bounds__(256) k_h0(
    const float* __restrict__ z, const float* __restrict__ Wp, const float* __restrict__ bp,
    float* __restrict__ cst, _Float16* __restrict__ hh0, _Float16* __restrict__ hl0)
{
    int bx = blockIdx.x;                             // grid 2048
    int m = bx >> 1;
    int n = ((bx & 1) << 8) + threadIdx.x;
    float acc = bp[n];
    const f4* zr = (const f4*)&z[m * 128];           // block-uniform (scalar loads)
    const f4* wr = (const f4*)&Wp[n * 128];
    #pragma unroll 8
    for (int p = 0; p < 32; ++p) {
        f4 zv = zr[p], wv = wr[p];
        acc += zv[0]*wv[0] + zv[1]*wv[1] + zv[2]*wv[2] + zv[3]*wv[3];
    }
    cst[m * 512 + n] = acc;
    _Float16 hi = (_Float16)acc;
    hh0[m * 512 + n] = hi;
    hl0[m * 512 + n] = (_Float16)(acc - (float)hi);
}

// ---------------- persistent step kernel ----------------
// PLAIN launch, grid 256 x 256 threads; 163 KB static LDS forces 1 block/CU so all blocks
// co-resident (R5/R6-proven). 16 INDEPENDENT row-group problems -> per-GROUP 16-block
// barriers, NO __threadfence (R5's killer). Cross-block state uses volatile vector
// accesses (single dwordx4 sc0 sc1 — R6's correctness, 2x fewer instructions, proper
// coalescing). __syncthreads drains vmcnt before the barrier arrive. Weights stay cached.
// Self-block state (yf, out, cst0 init, sB/bias/Wout loads) stays ordinary/cached.

__device__ __forceinline__ void group_barrier(unsigned* gbar)
{
    __syncthreads();    // drains each wave's vmcnt -> all coherent stores globally visible
    if (threadIdx.x == 0) {
        unsigned g = __hip_atomic_load(&gbar[1], __ATOMIC_RELAXED, __HIP_MEMORY_SCOPE_AGENT);
        unsigned a = __hip_atomic_fetch_add(&gbar[0], 1u, __ATOMIC_RELAXED, __HIP_MEMORY_SCOPE_AGENT);
        if (a == 15u) {
            __hip_atomic_store(&gbar[0], 0u, __ATOMIC_RELAXED, __HIP_MEMORY_SCOPE_AGENT);
            __hip_atomic_store(&gbar[1], g + 1u, __ATOMIC_RELAXED, __HIP_MEMORY_SCOPE_AGENT);
        } else {
            while (__hip_atomic_load(&gbar[1], __ATOMIC_RELAXED, __HIP_MEMORY_SCOPE_AGENT) == g)
                __builtin_amdgcn_s_sleep(2);
        }
    }
    __syncthreads();
}

__device__ __forceinline__ void resolve_y(
    int t, int row, int c4, f4 bo4,
    const float* __restrict__ yf_in, float* __restrict__ yf_out,
    const float* __restrict__ dl_in,
    _Float16* __restrict__ yh_out, _Float16* __restrict__ yl_out,
    float* __restrict__ out)
{
    f4 a = *(const f4*)&yf_in[row * 64 + c4];        // self-block: ordinary
    a += bo4;
    #pragma unroll
    for (int sp = 0; sp < 16; ++sp)
        a += cldf4(&dl_in[sp * 65536 + row * 64 + c4]);   // cross-block: coherent
    *(f4*)&yf_out[row * 64 + c4] = a;                // self-block
    *(f4*)&out[row * 8192 + (t - 1) * 64 + c4] = a;  // host-read only
    _Float16 hi4[4], lo4[4];
    #pragma unroll
    for (int x = 0; x < 4; ++x) {
        hi4[x] = (_Float16)a[x];
        lo4[x] = (_Float16)(a[x] - (float)hi4[x]);
    }
    cst64v(&yh_out[row * 64 + c4], *(u32x2*)hi4);    // cross-block: coherent
    cst64v(&yl_out[row * 64 + c4], *(u32x2*)lo4);
}

extern "C" __global__ void __launch_bounds__(256, 1) k_persist(
    const _Float16* __restrict__ WA, const _Float16* __restrict__ WB,
    const float* __restrict__ b0v, const float* __restrict__ b1v,
    const _Float16* __restrict__ WoB, const float* __restrict__ bout,
    _Float16* __restrict__ hhA, _Float16* __restrict__ hhB,
    _Float16* __restrict__ hlA, _Float16* __restrict__ hlB,
    const float* __restrict__ cst0,
    float* __restrict__ yfA, float* __restrict__ yfB,
    _Float16* __restrict__ yhA, _Float16* __restrict__ yhB,
    _Float16* __restrict__ ylA, _Float16* __restrict__ ylB,
    float* __restrict__ dlA, float* __restrict__ dlB,
    float* __restrict__ out,
    unsigned* bar)
{
    __shared__ __align__(16) unsigned char smem[163328];
    _Float16* sB  = (_Float16*)smem;                         // [96][SBS] = 112,128 B (persistent)
    _Float16* sAh = (_Float16*)(smem + 112128);              // [64][LDAH] = 25,600
    _Float16* sAl = (_Float16*)(smem + 137728);              // 25,600 (ends 163,328)
    float*    sEx = (float*)(smem + 112128);                 // overlay [4][64][EXS] = 36,864
    _Float16* sHh = (_Float16*)(smem + 148992);              // [64][HSTR] = 5,120
    _Float16* sHl = (_Float16*)(smem + 154112);              // 5,120 (ends 159,232)

    const int tid = threadIdx.x;
    const int bx  = blockIdx.x;
    const int xcd = bx & 7, slot = bx >> 3;                  // round-robin dispatch heuristic
    const int mt  = xcd * 2 + (slot >> 4);                   // same-mt blocks likely share an XCD
    const int s   = slot & 15;
    const int m0  = mt * 64, j0 = s * 32;
    unsigned* gbar = bar + mt * 64;                          // per-group barrier line

    const int wv = tid >> 6, lane = tid & 63, l15 = lane & 15, quad = lane >> 4;
    const int quad8 = quad * 8;

    // ---- persistent registers ----
    const int cm = tid >> 2, cjb = (tid & 3) * 8;            // cell: row cm, 8 cols at cjb
    const int cjcol = j0 + cjb;
    const int ccrow = (m0 + cm) * 512 + cjcol;
    f4 creg0 = *(const f4*)&cst0[ccrow];                     // c-state lives in regs
    f4 creg1 = *(const f4*)&cst0[ccrow + 4];
    f4 bi[8];                                                // bias: [2*gate + half4]
    #pragma unroll
    for (int g = 0; g < 4; ++g) {
        bi[2*g]   = *(const f4*)&b0v[g * 512 + cjcol];
        bi[2*g+1] = *(const f4*)&b0v[g * 512 + cjcol + 4];
    }
    half8 bw = *(const half8*)&WoB[(wv * 16 + l15) * 512 + j0 + quad8];
    f4 bo4 = *(const f4*)&bout[(tid & 15) * 4];

    // ---- load sB once: WB rows for quadrants 0..2, cols j0..j0+31 ----
    #pragma unroll
    for (int u = 0; u < 27; ++u) {
        int idx = u * 256 + tid;                             // 96 rows x 72 units of 8 halves
        int r = idx / 72, c = (idx % 72) * 8;
        int gr = (r >> 5) * 512 + j0 + (r & 31);
        *(u32x4*)&sB[r * SBS + c] = *(const u32x4*)&WB[gr * 576 + c];
    }

    // per-thread staging coordinates: 6 x 16B x 2 streams covers 64 rows x 192 halves
    int rr[6], cc6[6];
    #pragma unroll
    for (int it = 0; it < 6; ++it) {
        int i4 = it * 256 + tid;
        rr[it]  = i4 / 24;
        cc6[it] = (i4 % 24) * 8;
    }

    const int brow0 = (wv * 512 + j0 + l15) * 576;
    const int brow1 = (wv * 512 + j0 + 16 + l15) * 576;

    // rotating buffer pointers (parity of t)
    const _Float16 *hhin = hhA, *hlin = hlA;
    _Float16 *hhout = hhB, *hlout = hlB;
    const float *yfin = yfA;  float *yfout = yfB;
    _Float16 *yhout = yhB, *ylout = ylB;
    const _Float16 *yhin = yhA, *ylin = ylA;
    const float *dlin = dlB;  float *dlout = dlA;

    f4 zero = {0.0f, 0.0f, 0.0f, 0.0f};

    #pragma unroll 1
    for (int t = 0; t < 128; ++t) {
        if (t == 1) {                                        // switch to combined bias
            #pragma unroll
            for (int g = 0; g < 4; ++g) {
                bi[2*g]   = *(const f4*)&b1v[g * 512 + cjcol];
                bi[2*g+1] = *(const f4*)&b1v[g * 512 + cjcol + 4];
            }
        }
        const bool useg = (t == 0) || (wv == 3);             // global-streamed B path (L2-hot)
        const _Float16* Wc = (t == 0) ? WA : WB;

        f4 acc[4][2];
        #pragma unroll
        for (int a = 0; a < 4; ++a) { acc[a][0] = zero; acc[a][1] = zero; }

        half8 bv0[2][6], bv1[2][6];
        if (useg) {
            #pragma unroll
            for (int kc = 0; kc < 6; ++kc) {
                bv0[0][kc] = *(const half8*)&Wc[brow0 + kc * 32 + quad8];
                bv1[0][kc] = *(const half8*)&Wc[brow1 + kc * 32 + quad8];
            }
        }
        // stage chunk 0 (B-cols 0..191: y part + h[0..127]) — coherent reads of group state
        #pragma unroll
        for (int it = 0; it < 6; ++it) {
            int r = rr[it], cc = cc6[it];
            const _Float16 *sh, *sl;
            if (cc < 64) { sh = &yhin[(m0 + r) * 64 + cc];         sl = &ylin[(m0 + r) * 64 + cc]; }
            else         { sh = &hhin[(m0 + r) * 512 + (cc - 64)]; sl = &hlin[(m0 + r) * 512 + (cc - 64)]; }
            *(u32x4*)&sAh[r * LDAH + cc] = cld128(sh);
            *(u32x4*)&sAl[r * LDAH + cc] = cld128(sl);
        }

        u32x4 regH[6], regL[6];
        #pragma unroll
        for (int ch = 0; ch < 3; ++ch) {
            if (ch < 2) {
                #pragma unroll
                for (int it = 0; it < 6; ++it) {             // next chunk A (pure h stream)
                    int c = (ch + 1) * 192 + cc6[it] - 64;
                    regH[it] = cld128(&hhin[(m0 + rr[it]) * 512 + c]);
                    regL[it] = cld128(&hlin[(m0 + rr[it]) * 512 + c]);
                }
                if (useg) {
                    #pragma unroll
                    for (int kc = 0; kc < 6; ++kc) {         // next chunk B
                        bv0[(ch + 1) & 1][kc] = *(const half8*)&Wc[brow0 + (ch + 1) * 192 + kc * 32 + quad8];
                        bv1[(ch + 1) & 1][kc] = *(const half8*)&Wc[brow1 + (ch + 1) * 192 + kc * 32 + quad8];
                    }
                }
            }
            __syncthreads();                                 // this chunk's LDS writes visible
            #pragma unroll
            for (int kc = 0; kc < 6; ++kc) {
                int kq = kc * 32 + quad8;
                half8 b0, b1;
                if (useg) { b0 = bv0[ch & 1][kc]; b1 = bv1[ch & 1][kc]; }
                else {
                    int bcol = ch * 192 + kc * 32 + quad8;
                    b0 = *(const half8*)&sB[(wv * 32 +      l15) * SBS + bcol];
                    b1 = *(const half8*)&sB[(wv * 32 + 16 + l15) * SBS + bcol];
                }
                half8 ah0 = *(const half8*)&sAh[(l15     ) * LDAH + kq];
                half8 ah1 = *(const half8*)&sAh[(l15 + 16) * LDAH + kq];
                half8 ah2 = *(const half8*)&sAh[(l15 + 32) * LDAH + kq];
                half8 ah3 = *(const half8*)&sAh[(l15 + 48) * LDAH + kq];
                acc[0][0] = __builtin_amdgcn_mfma_f32_16x16x32_f16(ah0, b0, acc[0][0], 0, 0, 0);
                acc[1][0] = __builtin_amdgcn_mfma_f32_16x16x32_f16(ah1, b0, acc[1][0], 0, 0, 0);
                acc[2][0] = __builtin_amdgcn_mfma_f32_16x16x32_f16(ah2, b0, acc[2][0], 0, 0, 0);
                acc[3][0] = __builtin_amdgcn_mfma_f32_16x16x32_f16(ah3, b0, acc[3][0], 0, 0, 0);
                acc[0][1] = __builtin_amdgcn_mfma_f32_16x16x32_f16(ah0, b1, acc[0][1], 0, 0, 0);
                acc[1][1] = __builtin_amdgcn_mfma_f32_16x16x32_f16(ah1, b1, acc[1][1], 0, 0, 0);
                acc[2][1] = __builtin_amdgcn_mfma_f32_16x16x32_f16(ah2, b1, acc[2][1], 0, 0, 0);
                acc[3][1] = __builtin_amdgcn_mfma_f32_16x16x32_f16(ah3, b1, acc[3][1], 0, 0, 0);
                half8 al0 = *(const half8*)&sAl[(l15     ) * LDAH + kq];
                half8 al1 = *(const half8*)&sAl[(l15 + 16) * LDAH + kq];
                half8 al2 = *(const half8*)&sAl[(l15 + 32) * LDAH + kq];
                half8 al3 = *(const half8*)&sAl[(l15 + 48) * LDAH + kq];
                acc[0][0] = __builtin_amdgcn_mfma_f32_16x16x32_f16(al0, b0, acc[0][0], 0, 0, 0);
                acc[1][0] = __builtin_amdgcn_mfma_f32_16x16x32_f16(al1, b0, acc[1][0], 0, 0, 0);
                acc[2][0] = __builtin_amdgcn_mfma_f32_16x16x32_f16(al2, b0, acc[2][0], 0, 0, 0);
                acc[3][0] = __builtin_amdgcn_mfma_f32_16x16x32_f16(al3, b0, acc[3][0], 0, 0, 0);
                acc[0][1] = __builtin_amdgcn_mfma_f32_16x16x32_f16(al0, b1, acc[0][1], 0, 0, 0);
                acc[1][1] = __builtin_amdgcn_mfma_f32_16x16x32_f16(al1, b1, acc[1][1], 0, 0, 0);
                acc[2][1] = __builtin_amdgcn_mfma_f32_16x16x32_f16(al2, b1, acc[2][1], 0, 0, 0);
                acc[3][1] = __builtin_amdgcn_mfma_f32_16x16x32_f16(al3, b1, acc[3][1], 0, 0, 0);
            }
            if (ch < 2) {
                __syncthreads();                             // all reads of sA done
                #pragma unroll
                for (int it = 0; it < 6; ++it) {             // write-late half of T14 split
                    *(u32x4*)&sAh[rr[it] * LDAH + cc6[it]] = regH[it];
                    *(u32x4*)&sAl[rr[it] * LDAH + cc6[it]] = regL[it];
                }
            }
        }
        __syncthreads();                                     // sA dead -> overlay exchange

        // gate exchange: D layout col=lane&15 (gate col), row=quad*4+reg (m)
        #pragma unroll
        for (int a = 0; a < 4; ++a)
            #pragma unroll
            for (int b = 0; b < 2; ++b)
                #pragma unroll
                for (int r = 0; r < 4; ++r)
                    sEx[(wv * 64 + a * 16 + quad * 4 + r) * EXS + b * 16 + l15] = acc[a][b][r];
        __syncthreads();

        // LSTM cell update: row cm, 8 cols at cjb; c-state in regs
        {
            f4 gI0 = *(const f4*)&sEx[(0 * 64 + cm) * EXS + cjb];
            f4 gI1 = *(const f4*)&sEx[(0 * 64 + cm) * EXS + cjb + 4];
            f4 gF0 = *(const f4*)&sEx[(1 * 64 + cm) * EXS + cjb];
            f4 gF1 = *(const f4*)&sEx[(1 * 64 + cm) * EXS + cjb + 4];
            f4 gG0 = *(const f4*)&sEx[(2 * 64 + cm) * EXS + cjb];
            f4 gG1 = *(const f4*)&sEx[(2 * 64 + cm) * EXS + cjb + 4];
            f4 gO0 = *(const f4*)&sEx[(3 * 64 + cm) * EXS + cjb];
            f4 gO1 = *(const f4*)&sEx[(3 * 64 + cm) * EXS + cjb + 4];
            _Float16 hi8[8], lo8[8];
            #pragma unroll
            for (int x = 0; x < 4; ++x) {
                float iv = sigm(gI0[x] + bi[0][x]);
                float fv = sigm(gF0[x] + bi[2][x]);
                float gv = tanh_(gG0[x] + bi[4][x]);
                float ov = sigm(gO0[x] + bi[6][x]);
                float cn = fv * creg0[x] + iv * gv;
                float hn = ov * tanh_(cn);
                creg0[x] = cn;
                _Float16 hi = (_Float16)hn;
                hi8[x] = hi;
                lo8[x] = (_Float16)(hn - (float)hi);
            }
            #pragma unroll
            for (int x = 0; x < 4; ++x) {
                float iv = sigm(gI1[x] + bi[1][x]);
                float fv = sigm(gF1[x] + bi[3][x]);
                float gv = tanh_(gG1[x] + bi[5][x]);
                float ov = sigm(gO1[x] + bi[7][x]);
                float cn = fv * creg1[x] + iv * gv;
                float hn = ov * tanh_(cn);
                creg1[x] = cn;
                _Float16 hi = (_Float16)hn;
                hi8[4 + x] = hi;
                lo8[4 + x] = (_Float16)(hn - (float)hi);
            }
            cst128(&hhout[ccrow], *(u32x4*)hi8);             // cross-block: coherent
            cst128(&hlout[ccrow], *(u32x4*)lo8);
            *(u32x4*)&sHh[cm * HSTR + cjb]  = *(u32x4*)hi8;
            *(u32x4*)&sHl[cm * HSTR + cjb]  = *(u32x4*)lo8;
        }
        __syncthreads();

        // Delta partial: dl_out[s] = (h_hi+h_lo)(strip) @ Wout^T; wave wv -> out-cols wv*16..
        {
            f4 d[4];
            #pragma unroll
            for (int a = 0; a < 4; ++a) d[a] = zero;
            #pragma unroll
            for (int a = 0; a < 4; ++a) {
                half8 ahh = *(const half8*)&sHh[(a * 16 + l15) * HSTR + quad8];
                half8 ahl = *(const half8*)&sHl[(a * 16 + l15) * HSTR + quad8];
                d[a] = __builtin_amdgcn_mfma_f32_16x16x32_f16(ahh, bw, d[a], 0, 0, 0);
                d[a] = __builtin_amdgcn_mfma_f32_16x16x32_f16(ahl, bw, d[a], 0, 0, 0);
            }
            #pragma unroll
            for (int a = 0; a < 4; ++a)
                #pragma unroll
                for (int r = 0; r < 4; ++r)
                    cst32f(&dlout[s * 65536 + (m0 + a * 16 + quad * 4 + r) * 64 + wv * 16 + l15],
                           d[a][r]);                         // cross-block: coherent
        }

        // tail resolve of y_{t-1} (reads only step t-1 data)
        if (t >= 1 && tid < 64) {
            int row = m0 + s * 4 + (tid >> 4);
            int c4  = (tid & 15) * 4;
            resolve_y(t, row, c4, bo4, yfin, yfout, dlin, yhout, ylout, out);
        }

        group_barrier(gbar);

        // swap parities
        { const _Float16* p = hhin; hhin = hhout; hhout = (_Float16*)p; }
        { const _Float16* p = hlin; hlin = hlout; hlout = (_Float16*)p; }
        { const float*    p = yfin; yfin = yfout; yfout = (float*)p; }
        { const _Float16* p = yhin; yhin = yhout; yhout = (_Float16*)p; }
        { const _Float16* p = ylin; ylin = ylout; ylout = (_Float16*)p; }
        { const float*    p = dlin; dlin = dlout; dlout = (float*)p; }
    }

    // final resolve of y_127 (t = 128)
    if (tid < 64) {
        int row = m0 + s * 4 + (tid >> 4);
        int c4  = (tid & 15) * 4;
        resolve_y(128, row, c4, bo4, yfin, yfout, dlin, yhout, ylout, out);
    }
}

// ---------------- host ----------------
extern "C" void kernel_launch(void* const* d_in, const int* in_sizes, int n_in,
                              void* d_out, int out_size, void* d_ws, size_t ws_size,
                              hipStream_t stream)
{
    const float* z   = (const float*)d_in[0];
    const float* x   = (const float*)d_in[1];
    const float* Wih = (const float*)d_in[2];
    const float* Whh = (const float*)d_in[3];
    const float* bih = (const float*)d_in[4];
    const float* bhh = (const float*)d_in[5];
    const float* Wp  = (const float*)d_in[6];
    const float* bp  = (const float*)d_in[7];
    const float* Wo  = (const float*)d_in[8];
    const float* bo  = (const float*)d_in[9];

    char* w = (char*)d_ws;
    _Float16* WA  = (_Float16*)w; w += 2359296;   // [2048][576] fp16
    _Float16* WB  = (_Float16*)w; w += 2359296;
    _Float16* WoB = (_Float16*)w; w += 65536;     // [64][512] fp16
    float* b0v = (float*)w; w += 8192;
    float* b1v = (float*)w; w += 8192;
    _Float16* hh[2];
    hh[0] = (_Float16*)w; w += 1048576;
    hh[1] = (_Float16*)w; w += 1048576;
    _Float16* hl[2];
    hl[0] = (_Float16*)w; w += 1048576;
    hl[1] = (_Float16*)w; w += 1048576;
    float* cst = (float*)w; w += 2097152;
    float* yf[2];
    yf[0] = (float*)w; w += 262144;
    yf[1] = (float*)w; w += 262144;
    _Float16* yh[2];
    yh[0] = (_Float16*)w; w += 131072;
    yh[1] = (_Float16*)w; w += 131072;
    _Float16* yl[2];
    yl[0] = (_Float16*)w; w += 131072;
    yl[1] = (_Float16*)w; w += 131072;
    float* dl[2];
    dl[0] = (float*)w; w += 4194304;              // [16][1024][64] fp32
    dl[1] = (float*)w; w += 4194304;
    unsigned* bar = (unsigned*)w; w += 4096;      // 16 group barriers, 256B apart
    float* out = (float*)d_out;

    k_wcat<<<4608, 256, 0, stream>>>(Wih, Whh, WA, WB);
    k_comb<<<4096, 256, 0, stream>>>(Wih, Whh, Wo, WB);
    k_misc<<<396, 256, 0, stream>>>(Wo, bih, bhh, Wih, bo, x, WoB, b0v, b1v,
                                    yf[0], yf[1], yh[0], yh[1], yl[0], yl[1], bar);
    k_h0<<<2048, 256, 0, stream>>>(z, Wp, bp, cst, hh[0], hl[0]);

    // plain launch (graph-capturable); co-residency by construction:
    // grid 256 == CU count, 163 KB LDS -> exactly 1 block/CU (R5/R6-proven).
    k_persist<<<256, 256, 0, stream>>>(
        WA, WB, b0v, b1v, WoB, bo,
        hh[0], hh[1], hl[0], hl[1],
        cst,
        yf[0], yf[1], yh[0], yh[1], yl[0], yl[1],
        dl[0], dl[1],
        out, bar);
}

// Round 11
// 2000.474 us; speedup vs baseline: 1.7559x; 1.7559x over previous
//
#include <hip/hip_runtime.h>
#include <stdint.h>

typedef _Float16 half8 __attribute__((ext_vector_type(8)));  // 8 fp16 (4 VGPR) MFMA frag
typedef __attribute__((ext_vector_type(4))) float f4;        // fp32x4 accum
typedef __attribute__((ext_vector_type(4))) unsigned int u32x4;
typedef __attribute__((ext_vector_type(2))) unsigned int u32x2;

#define LDAH 200   // halves per LDS A row (192 data + 8 pad; conflict-free b128, 16B aligned)
#define EXS  34    // exchange stride (floats)
#define HSTR 40    // sH stride (halves), 80B: 16B-aligned

__device__ __forceinline__ float sigm(float x) { return 1.0f / (1.0f + __expf(-x)); }
__device__ __forceinline__ float tanh_(float x) { return 1.0f - 2.0f / (__expf(2.0f * x) + 1.0f); } // overflow-safe

// ---------------- prologue kernels ----------------

// W_catA[2048][576] = [W_ih | W_hh] fp16 ; also W_ih part of W_catB
extern "C" __global__ void __launch_bounds__(256) k_wcat(
    const float* __restrict__ Wih, const float* __restrict__ Whh,
    _Float16* __restrict__ WA, _Float16* __restrict__ WB)
{
    int idx = blockIdx.x * 256 + threadIdx.x;        // grid 4608 -> exactly 2048*576
    int n = idx / 576, k = idx % 576;
    float v = (k < 64) ? Wih[n * 64 + k] : Whh[n * 512 + (k - 64)];
    _Float16 b = (_Float16)v;
    WA[idx] = b;
    if (k < 64) WB[idx] = b;
}

// W_catB[n][64+k] = W_hh[n][k] + sum_p W_ih[n][p] * W_out[p][k]   (fp32 accum, fp16 store)
extern "C" __global__ void __launch_bounds__(256) k_comb(
    const float* __restrict__ Wih, const float* __restrict__ Whh,
    const float* __restrict__ Wo, _Float16* __restrict__ WB)
{
    int bx = blockIdx.x;                             // grid 4096
    int n = bx >> 1;
    int kh = ((bx & 1) << 8) + threadIdx.x;          // 0..511
    float acc = Whh[n * 512 + kh];
    #pragma unroll 16
    for (int p = 0; p < 64; ++p)
        acc += Wih[n * 64 + p] * Wo[p * 512 + kh];
    WB[n * 576 + 64 + kh] = (_Float16)acc;
}

// Wout fp16, bias0 = b_ih+b_hh, bias1 = bias0 + W_ih@b_out, y_{-1} init (fp32 + fp16 hi/lo, both parities)
extern "C" __global__ void __launch_bounds__(256) k_misc(
    const float* __restrict__ Wo, const float* __restrict__ bih, const float* __restrict__ bhh,
    const float* __restrict__ Wih, const float* __restrict__ bo, const float* __restrict__ x,
    _Float16* __restrict__ WoB, float* __restrict__ b0v, float* __restrict__ b1v,
    float* __restrict__ yf0, float* __restrict__ yf1,
    _Float16* __restrict__ yh0, _Float16* __restrict__ yh1,
    _Float16* __restrict__ yl0, _Float16* __restrict__ yl1)
{
    int idx = blockIdx.x * 256 + threadIdx.x;        // grid 392
    if (idx < 32768) { WoB[idx] = (_Float16)Wo[idx]; return; }
    if (idx < 34816) {
        int n = idx - 32768;
        float b = bih[n] + bhh[n];
        b0v[n] = b;
        float a = b;
        #pragma unroll 16
        for (int p = 0; p < 64; ++p) a += Wih[n * 64 + p] * bo[p];
        b1v[n] = a;
        return;
    }
    if (idx < 100352) {
        int e = idx - 34816;
        int m = e >> 6, nn = e & 63;
        float v = x[m * 2048 + 31 * 64 + nn];        // x[:, -1, :]
        yf0[e] = v; yf1[e] = v;
        _Float16 hi = (_Float16)v;
        _Float16 lo = (_Float16)(v - (float)hi);
        yh0[e] = hi; yh1[e] = hi;
        yl0[e] = lo; yl1[e] = lo;
    }
}

// h0 = z @ Wproj^T + b_proj ; c0 = h0 ; h stored fp16 hi/lo
extern "C" __global__ void __launch_bounds__(256) k_h0(
    const float* __restrict__ z, const float* __restrict__ Wp, const float* __restrict__ bp,
    float* __restrict__ cst, _Float16* __restrict__ hh0, _Float16* __restrict__ hl0)
{
    int bx = blockIdx.x;                             // grid 2048
    int m = bx >> 1;
    int n = ((bx & 1) << 8) + threadIdx.x;
    float acc = bp[n];
    const f4* zr = (const f4*)&z[m * 128];           // block-uniform (scalar loads)
    const f4* wr = (const f4*)&Wp[n * 128];
    #pragma unroll 8
    for (int p = 0; p < 32; ++p) {
        f4 zv = zr[p], wv = wr[p];
        acc += zv[0]*wv[0] + zv[1]*wv[1] + zv[2]*wv[2] + zv[3]*wv[3];
    }
    cst[m * 512 + n] = acc;
    _Float16 hi = (_Float16)acc;
    hh0[m * 512 + n] = hi;
    hl0[m * 512 + n] = (_Float16)(acc - (float)hi);
}

// ---------------- per-step kernel ----------------
// R2 structure (best measured: 1994 us). grid 256 = 16 mt x 16 s: rows m0..m0+64,
// h-cols j0..j0+32 (all 4 gate quadrants). GEMM: K=576 B-cols, each B fragment feeds
// BOTH hi-A and lo-A MFMAs (B traffic halved vs split-K). A staged as two LDS streams
// (sAh, sAl), 3 chunks x 192 B-cols, T14 issue-early/write-late staging.
// t in [0,128]; t==128 -> resolution of y_127 only.
extern "C" __global__ void __launch_bounds__(256, 1) k_step(
    int t,
    const _Float16* __restrict__ Wcat,         // [2048][576] fp16 (A or B variant)
    const float* __restrict__ bias,            // [2048]
    const _Float16* __restrict__ Wout,         // [64][512] fp16
    const float* __restrict__ bout,            // [64]
    const _Float16* __restrict__ hh_in, const _Float16* __restrict__ hl_in,  // [1024][512]
    _Float16* __restrict__ hh_out, _Float16* __restrict__ hl_out,
    float* __restrict__ cst,                   // [1024][512] fp32 (in-place)
    const float* __restrict__ yf_in, float* __restrict__ yf_out,             // [1024][64]
    const _Float16* __restrict__ yh_in, _Float16* __restrict__ yh_out,
    const _Float16* __restrict__ yl_in, _Float16* __restrict__ yl_out,
    const float* __restrict__ dl_in, float* __restrict__ dl_out,             // [16][1024][64]
    float* __restrict__ out)                   // [1024][128][64]
{
    __shared__ __align__(16) unsigned char smem[61440];
    _Float16* sAh = (_Float16*)smem;                             // [64][LDAH] = 25,600 B
    _Float16* sAl = (_Float16*)(smem + 25600);                   // [64][LDAH] = 25,600 B
    float*    sEx = (float*)smem;                                // overlay: [4][64][EXS] = 34,816 B
    _Float16* sHh = (_Float16*)(smem + 51200);                   // [64][HSTR] = 5,120 B
    _Float16* sHl = (_Float16*)(smem + 56320);                   // [64][HSTR]

    const int tid = threadIdx.x;
    const int bx  = blockIdx.x;
    const int mt  = bx >> 4, s = bx & 15;
    const int m0  = mt * 64, j0 = s * 32;

    // ---- resolve y_{t-1} = y_{t-2} + b_out + sum_s Delta_{t-1,s} (4 rows per block) ----
    if (t >= 1 && tid < 64) {
        int row = m0 + s * 4 + (tid >> 4);
        int c4  = (tid & 15) * 4;
        f4 a = *(const f4*)&yf_in[row * 64 + c4];
        a += *(const f4*)&bout[c4];
        #pragma unroll
        for (int sp = 0; sp < 16; ++sp)
            a += *(const f4*)&dl_in[sp * 65536 + row * 64 + c4];
        *(f4*)&yf_out[row * 64 + c4] = a;
        *(f4*)&out[row * 8192 + (t - 1) * 64 + c4] = a;
        _Float16 hi4[4], lo4[4];
        #pragma unroll
        for (int x = 0; x < 4; ++x) {
            hi4[x] = (_Float16)a[x];
            lo4[x] = (_Float16)(a[x] - (float)hi4[x]);
        }
        *(u32x2*)&yh_out[row * 64 + c4] = *(u32x2*)hi4;
        *(u32x2*)&yl_out[row * 64 + c4] = *(u32x2*)lo4;
    }
    if (t >= 128) return;

    const int wv = tid >> 6, lane = tid & 63, l15 = lane & 15, quad = lane >> 4;
    const int quad8 = quad * 8;

    f4 zero = {0.0f, 0.0f, 0.0f, 0.0f};
    f4 acc[4][2];
    #pragma unroll
    for (int a = 0; a < 4; ++a) { acc[a][0] = zero; acc[a][1] = zero; }

    const int brow0 = (wv * 512 + j0 + l15) * 576;
    const int brow1 = (wv * 512 + j0 + 16 + l15) * 576;

    // per-thread staging coordinates (fixed across chunks): 6 x 16B covers 64 rows x 192 halves
    int rr[6], cc6[6];
    #pragma unroll
    for (int it = 0; it < 6; ++it) {
        int i4 = it * 256 + tid;
        rr[it]  = i4 / 24;
        cc6[it] = (i4 % 24) * 8;
    }

    // ---- prologue: stage chunk 0 (B-cols 0..191: y part + h[0..127]) ----
    #pragma unroll
    for (int it = 0; it < 6; ++it) {
        int r = rr[it], cc = cc6[it];
        const _Float16 *sh, *sl;
        if (cc < 64) { sh = &yh_in[(m0 + r) * 64 + cc];        sl = &yl_in[(m0 + r) * 64 + cc]; }
        else         { sh = &hh_in[(m0 + r) * 512 + (cc - 64)]; sl = &hl_in[(m0 + r) * 512 + (cc - 64)]; }
        *(u32x4*)&sAh[r * LDAH + cc] = *(const u32x4*)sh;
        *(u32x4*)&sAl[r * LDAH + cc] = *(const u32x4*)sl;
    }

    // ---- 3 chunks of 192 B-cols; B loaded once, feeds hi AND lo MFMAs ----
    u32x4 regH[6], regL[6];
    #pragma unroll
    for (int ch = 0; ch < 3; ++ch) {
        // B prefetch for this chunk (12 loads, L2-hot)
        half8 bv0[6], bv1[6];
        #pragma unroll
        for (int kc = 0; kc < 6; ++kc) {
            int bq = ch * 192 + kc * 32 + quad8;
            bv0[kc] = *(const half8*)&Wcat[brow0 + bq];
            bv1[kc] = *(const half8*)&Wcat[brow1 + bq];
        }
        // T14: issue next chunk's staging loads now; latency hides under MFMA phase
        if (ch < 2) {
            #pragma unroll
            for (int it = 0; it < 6; ++it) {
                int c = (ch + 1) * 192 + cc6[it] - 64;   // >= 128: pure h stream
                regH[it] = *(const u32x4*)&hh_in[(m0 + rr[it]) * 512 + c];
                regL[it] = *(const u32x4*)&hl_in[(m0 + rr[it]) * 512 + c];
            }
        }
        __syncthreads();                                 // this chunk's LDS writes visible
        #pragma unroll
        for (int kc = 0; kc < 6; ++kc) {
            int kq = kc * 32 + quad8;
            half8 ah0 = *(const half8*)&sAh[(l15     ) * LDAH + kq];
            half8 ah1 = *(const half8*)&sAh[(l15 + 16) * LDAH + kq];
            half8 ah2 = *(const half8*)&sAh[(l15 + 32) * LDAH + kq];
            half8 ah3 = *(const half8*)&sAh[(l15 + 48) * LDAH + kq];
            half8 al0 = *(const half8*)&sAl[(l15     ) * LDAH + kq];
            half8 al1 = *(const half8*)&sAl[(l15 + 16) * LDAH + kq];
            half8 al2 = *(const half8*)&sAl[(l15 + 32) * LDAH + kq];
            half8 al3 = *(const half8*)&sAl[(l15 + 48) * LDAH + kq];
            acc[0][0] = __builtin_amdgcn_mfma_f32_16x16x32_f16(ah0, bv0[kc], acc[0][0], 0, 0, 0);
            acc[1][0] = __builtin_amdgcn_mfma_f32_16x16x32_f16(ah1, bv0[kc], acc[1][0], 0, 0, 0);
            acc[2][0] = __builtin_amdgcn_mfma_f32_16x16x32_f16(ah2, bv0[kc], acc[2][0], 0, 0, 0);
            acc[3][0] = __builtin_amdgcn_mfma_f32_16x16x32_f16(ah3, bv0[kc], acc[3][0], 0, 0, 0);
            acc[0][1] = __builtin_amdgcn_mfma_f32_16x16x32_f16(ah0, bv1[kc], acc[0][1], 0, 0, 0);
            acc[1][1] = __builtin_amdgcn_mfma_f32_16x16x32_f16(ah1, bv1[kc], acc[1][1], 0, 0, 0);
            acc[2][1] = __builtin_amdgcn_mfma_f32_16x16x32_f16(ah2, bv1[kc], acc[2][1], 0, 0, 0);
            acc[3][1] = __builtin_amdgcn_mfma_f32_16x16x32_f16(ah3, bv1[kc], acc[3][1], 0, 0, 0);
            acc[0][0] = __builtin_amdgcn_mfma_f32_16x16x32_f16(al0, bv0[kc], acc[0][0], 0, 0, 0);
            acc[1][0] = __builtin_amdgcn_mfma_f32_16x16x32_f16(al1, bv0[kc], acc[1][0], 0, 0, 0);
            acc[2][0] = __builtin_amdgcn_mfma_f32_16x16x32_f16(al2, bv0[kc], acc[2][0], 0, 0, 0);
            acc[3][0] = __builtin_amdgcn_mfma_f32_16x16x32_f16(al3, bv0[kc], acc[3][0], 0, 0, 0);
            acc[0][1] = __builtin_amdgcn_mfma_f32_16x16x32_f16(al0, bv1[kc], acc[0][1], 0, 0, 0);
            acc[1][1] = __builtin_amdgcn_mfma_f32_16x16x32_f16(al1, bv1[kc], acc[1][1], 0, 0, 0);
            acc[2][1] = __builtin_amdgcn_mfma_f32_16x16x32_f16(al2, bv1[kc], acc[2][1], 0, 0, 0);
            acc[3][1] = __builtin_amdgcn_mfma_f32_16x16x32_f16(al3, bv1[kc], acc[3][1], 0, 0, 0);
        }
        if (ch < 2) {
            __syncthreads();                             // all reads of sA done
            #pragma unroll
            for (int it = 0; it < 6; ++it) {             // write-late half of T14 split
                *(u32x4*)&sAh[rr[it] * LDAH + cc6[it]] = regH[it];
                *(u32x4*)&sAl[rr[it] * LDAH + cc6[it]] = regL[it];
            }
        }
    }
    __syncthreads();                                  // sA dead -> overlay exchange

    // ---- gate exchange: wave wv = quadrant wv (i,f,g,o). D layout: col=lane&15, row=quad*4+reg ----
    #pragma unroll
    for (int a = 0; a < 4; ++a)
        #pragma unroll
        for (int b = 0; b < 2; ++b)
            #pragma unroll
            for (int r = 0; r < 4; ++r)
                sEx[(wv * 64 + a * 16 + quad * 4 + r) * EXS + b * 16 + l15] = acc[a][b][r];
    __syncthreads();

    // ---- LSTM cell update: thread -> row m, 8 h-cols ----
    {
        int m = tid >> 2, jb = (tid & 3) * 8;
        int jcol = j0 + jb;
        int crow = (m0 + m) * 512 + jcol;
        f4 c0 = *(const f4*)&cst[crow];
        f4 c1 = *(const f4*)&cst[crow + 4];
        _Float16 hi8[8], lo8[8];
        #pragma unroll
        for (int x = 0; x < 8; ++x) {
            float gi = sEx[(0 * 64 + m) * EXS + jb + x] + bias[       jcol + x];
            float gf = sEx[(1 * 64 + m) * EXS + jb + x] + bias[ 512 + jcol + x];
            float gg = sEx[(2 * 64 + m) * EXS + jb + x] + bias[1024 + jcol + x];
            float go = sEx[(3 * 64 + m) * EXS + jb + x] + bias[1536 + jcol + x];
            float iv = sigm(gi), fv = sigm(gf), gv = tanh_(gg), ov = sigm(go);
            float cold = (x < 4) ? c0[x] : c1[x - 4];
            float cn = fv * cold + iv * gv;
            float hn = ov * tanh_(cn);
            if (x < 4) c0[x] = cn; else c1[x - 4] = cn;
            _Float16 hi = (_Float16)hn;
            hi8[x] = hi;
            lo8[x] = (_Float16)(hn - (float)hi);
        }
        *(f4*)&cst[crow]     = c0;
        *(f4*)&cst[crow + 4] = c1;
        *(u32x4*)&hh_out[crow]       = *(u32x4*)hi8;
        *(u32x4*)&hl_out[crow]       = *(u32x4*)lo8;
        *(u32x4*)&sHh[m * HSTR + jb] = *(u32x4*)hi8;
        *(u32x4*)&sHl[m * HSTR + jb] = *(u32x4*)lo8;
    }
    __syncthreads();

    // ---- Delta partial: dl_out[s] = (h_hi+h_lo)(strip) @ Wout^T, K=32 per m-tile ----
    {
        half8 bw = *(const half8*)&Wout[(wv * 16 + l15) * 512 + j0 + quad8];
        f4 d[4];
        #pragma unroll
        for (int a = 0; a < 4; ++a) d[a] = zero;
        #pragma unroll
        for (int a = 0; a < 4; ++a) {
            half8 ahh = *(const half8*)&sHh[(a * 16 + l15) * HSTR + quad8];
            half8 ahl = *(const half8*)&sHl[(a * 16 + l15) * HSTR + quad8];
            d[a] = __builtin_amdgcn_mfma_f32_16x16x32_f16(ahh, bw, d[a], 0, 0, 0);
            d[a] = __builtin_amdgcn_mfma_f32_16x16x32_f16(ahl, bw, d[a], 0, 0, 0);
        }
        #pragma unroll
        for (int a = 0; a < 4; ++a)
            #pragma unroll
            for (int r = 0; r < 4; ++r)
                dl_out[s * 65536 + (m0 + a * 16 + quad * 4 + r) * 64 + wv * 16 + l15] = d[a][r];
    }
}

// ---------------- host ----------------
extern "C" void kernel_launch(void* const* d_in, const int* in_sizes, int n_in,
                              void* d_out, int out_size, void* d_ws, size_t ws_size,
                              hipStream_t stream)
{
    const float* z   = (const float*)d_in[0];
    const float* x   = (const float*)d_in[1];
    const float* Wih = (const float*)d_in[2];
    const float* Whh = (const float*)d_in[3];
    const float* bih = (const float*)d_in[4];
    const float* bhh = (const float*)d_in[5];
    const float* Wp  = (const float*)d_in[6];
    const float* bp  = (const float*)d_in[7];
    const float* Wo  = (const float*)d_in[8];
    const float* bo  = (const float*)d_in[9];

    char* w = (char*)d_ws;
    _Float16* WA  = (_Float16*)w; w += 2359296;   // [2048][576] fp16
    _Float16* WB  = (_Float16*)w; w += 2359296;
    _Float16* WoB = (_Float16*)w; w += 65536;     // [64][512] fp16
    float* b0v = (float*)w; w += 8192;
    float* b1v = (float*)w; w += 8192;
    _Float16* hh[2];
    hh[0] = (_Float16*)w; w += 1048576;
    hh[1] = (_Float16*)w; w += 1048576;
    _Float16* hl[2];
    hl[0] = (_Float16*)w; w += 1048576;
    hl[1] = (_Float16*)w; w += 1048576;
    float* cst = (float*)w; w += 2097152;
    float* yf[2];
    yf[0] = (float*)w; w += 262144;
    yf[1] = (float*)w; w += 262144;
    _Float16* yh[2];
    yh[0] = (_Float16*)w; w += 131072;
    yh[1] = (_Float16*)w; w += 131072;
    _Float16* yl[2];
    yl[0] = (_Float16*)w; w += 131072;
    yl[1] = (_Float16*)w; w += 131072;
    float* dl[2];
    dl[0] = (float*)w; w += 4194304;              // [16][1024][64] fp32
    dl[1] = (float*)w; w += 4194304;
    float* out = (float*)d_out;

    k_wcat<<<4608, 256, 0, stream>>>(Wih, Whh, WA, WB);
    k_comb<<<4096, 256, 0, stream>>>(Wih, Whh, Wo, WB);
    k_misc<<<392, 256, 0, stream>>>(Wo, bih, bhh, Wih, bo, x, WoB, b0v, b1v,
                                    yf[0], yf[1], yh[0], yh[1], yl[0], yl[1]);
    k_h0<<<2048, 256, 0, stream>>>(z, Wp, bp, cst, hh[0], hl[0]);

    for (int t = 0; t <= 128; ++t) {
        k_step<<<256, 256, 0, stream>>>(t,
            (t == 0) ? WA : WB, (t == 0) ? b0v : b1v,
            WoB, bo,
            hh[t & 1], hl[t & 1], hh[(t + 1) & 1], hl[(t + 1) & 1],
            cst,
            yf[t & 1], yf[(t + 1) & 1],
            yh[t & 1], yh[(t + 1) & 1],
            yl[t & 1], yl[(t + 1) & 1],
            dl[(t + 1) & 1], dl[t & 1],
            out);
    }
}